// Round 10
// baseline (201.481 us; speedup 1.0000x reference)
//
#include <hip/hip_runtime.h>

#define NH 32
#define HD 128
#define PBS 16
#define HIDDEN (NH * HD)   // 4096
#define QKVN (3 * HIDDEN)  // 12288
#define NSPLIT 8
#define KC 512             // k-chunk staged in LDS

// out[b][n] = dot(x[b,:K], W[n,:K]) + bias[n], B=8 fixed.
// 256 thr = 4 waves, NR rows/wave. Double-buffered LDS x (1 barrier/chunk);
// both 256-wide j-pieces' weight loads issued up front (8KB/wave in flight).
template <int NR>
__global__ __launch_bounds__(256) void gemv_db(const float* __restrict__ x,
                                               const float* __restrict__ W,
                                               const float* __restrict__ bias,
                                               float* __restrict__ out,
                                               int N, int K) {
    __shared__ float xs[2][8][KC];
    const int tid  = threadIdx.x;
    const int lane = tid & 63;
    const int wid  = tid >> 6;
    const int n0   = blockIdx.x * (NR * 4) + wid * NR;
    const float* w0 = W + (size_t)n0 * K;
    const int bq  = tid >> 5;
    const int t32 = tid & 31;

    // stage chunk 0
    {
        const float* xb = x + (size_t)bq * K;
#pragma unroll
        for (int j = 0; j < 4; ++j) {
            const int off = (t32 + j * 32) * 4;
            *reinterpret_cast<float4*>(&xs[0][bq][off]) =
                *reinterpret_cast<const float4*>(xb + off);
        }
    }
    float acc[NR][8];
#pragma unroll
    for (int r = 0; r < NR; ++r)
#pragma unroll
        for (int b = 0; b < 8; ++b) acc[r][b] = 0.f;

    __syncthreads();
    int cur = 0;
    for (int kc = 0; kc < K; kc += KC) {
        // stage next chunk into the other buffer (no reader conflicts)
        if (kc + KC < K) {
            const float* xb = x + (size_t)bq * K + kc + KC;
#pragma unroll
            for (int j = 0; j < 4; ++j) {
                const int off = (t32 + j * 32) * 4;
                *reinterpret_cast<float4*>(&xs[cur ^ 1][bq][off]) =
                    *reinterpret_cast<const float4*>(xb + off);
            }
        }
        // issue ALL weight loads for this chunk, then compute
        const int kk0 = lane * 4;
        float4 w4a[NR], w4b[NR];
#pragma unroll
        for (int r = 0; r < NR; ++r)
            w4a[r] = *reinterpret_cast<const float4*>(w0 + (size_t)r * K + kc + kk0);
#pragma unroll
        for (int r = 0; r < NR; ++r)
            w4b[r] = *reinterpret_cast<const float4*>(w0 + (size_t)r * K + kc + kk0 + 256);
#pragma unroll
        for (int b = 0; b < 8; ++b) {
            const float4 x4 = *reinterpret_cast<const float4*>(&xs[cur][b][kk0]);
#pragma unroll
            for (int r = 0; r < NR; ++r)
                acc[r][b] += w4a[r].x * x4.x + w4a[r].y * x4.y +
                             w4a[r].z * x4.z + w4a[r].w * x4.w;
        }
#pragma unroll
        for (int b = 0; b < 8; ++b) {
            const float4 x4 = *reinterpret_cast<const float4*>(&xs[cur][b][kk0 + 256]);
#pragma unroll
            for (int r = 0; r < NR; ++r)
                acc[r][b] += w4b[r].x * x4.x + w4b[r].y * x4.y +
                             w4b[r].z * x4.z + w4b[r].w * x4.w;
        }
        __syncthreads();  // next chunk staged; cur fully consumed
        cur ^= 1;
    }
#pragma unroll
    for (int r = 0; r < NR; ++r)
#pragma unroll
        for (int b = 0; b < 8; ++b)
#pragma unroll
            for (int off = 32; off > 0; off >>= 1)
                acc[r][b] += __shfl_xor(acc[r][b], off, 64);
    if (lane == 0) {
#pragma unroll
        for (int r = 0; r < NR; ++r) {
            const float bv = bias ? bias[n0 + r] : 0.f;
#pragma unroll
            for (int b = 0; b < 8; ++b)
                out[(size_t)b * N + n0 + r] = acc[r][b] + bv;
        }
    }
}

// One-pass online-softmax partial with FUSED RoPE on q / fresh-k.
// One block per (b,h,split), 256 thr = 4 waves.
__global__ __launch_bounds__(256) void attn_part(const float* __restrict__ qkv,
                                                 const float* __restrict__ cosb,
                                                 const float* __restrict__ sinb,
                                                 const float* __restrict__ k_cache,
                                                 const float* __restrict__ v_cache,
                                                 const int* __restrict__ block_tables,
                                                 const int* __restrict__ slots,
                                                 const int* __restrict__ lengths,
                                                 float* __restrict__ part_o,
                                                 float* __restrict__ part_ml,
                                                 int S, int max_blocks) {
    const int split = blockIdx.x % NSPLIT;
    const int bh    = blockIdx.x / NSPLIT;
    const int b     = bh >> 5;
    const int h     = bh & 31;
    const int SP    = S / NSPLIT;       // 256
    const int base  = split * SP;

    __shared__ int   bt[64];            // SP/PBS = 16 used
    __shared__ float stage[4][HD + 2];

    const int tid  = threadIdx.x;
    const int lane = tid & 63;
    const int wid  = tid >> 6;
    const int nw   = 4;
    const int half = lane >> 5;
    const int l32  = lane & 31;

    const int nbt = SP / PBS;  // 16
    for (int i = tid; i < nbt; i += blockDim.x)
        bt[i] = block_tables[b * max_blocks + base / PBS + i];
    __syncthreads();

    const int slot_b = slots[b];
    const int len    = lengths[b];
    const float scale = 0.088388347648318447f;  // 1/sqrt(128)

    const float* qp   = qkv + (size_t)b * QKVN + h * HD;
    const float* newkp = qp + HIDDEN;
    const float* newvp = qp + 2 * HIDDEN;

    // load raw q and fresh-k fragments, apply RoPE in-register.
    // lane's dims d = l32*4..+3; partner (d ^ 64) lives at lane^16 (same half).
    float4 q4 = *reinterpret_cast<const float4*>(qp + l32 * 4);
    float4 kn4 = *reinterpret_cast<const float4*>(newkp + l32 * 4);
    {
        const float4 c4 = *reinterpret_cast<const float4*>(cosb + b * 64 + (l32 & 15) * 4);
        const float4 s4 = *reinterpret_cast<const float4*>(sinb + b * 64 + (l32 & 15) * 4);
        const float sgn = (l32 < 16) ? -1.f : 1.f;
        float4 qpr, kpr;
        qpr.x = __shfl_xor(q4.x, 16, 64);
        qpr.y = __shfl_xor(q4.y, 16, 64);
        qpr.z = __shfl_xor(q4.z, 16, 64);
        qpr.w = __shfl_xor(q4.w, 16, 64);
        kpr.x = __shfl_xor(kn4.x, 16, 64);
        kpr.y = __shfl_xor(kn4.y, 16, 64);
        kpr.z = __shfl_xor(kn4.z, 16, 64);
        kpr.w = __shfl_xor(kn4.w, 16, 64);
        q4.x = q4.x * c4.x + sgn * qpr.x * s4.x;
        q4.y = q4.y * c4.y + sgn * qpr.y * s4.y;
        q4.z = q4.z * c4.z + sgn * qpr.z * s4.z;
        q4.w = q4.w * c4.w + sgn * qpr.w * s4.w;
        kn4.x = kn4.x * c4.x + sgn * kpr.x * s4.x;
        kn4.y = kn4.y * c4.y + sgn * kpr.y * s4.y;
        kn4.z = kn4.z * c4.z + sgn * kpr.z * s4.z;
        kn4.w = kn4.w * c4.w + sgn * kpr.w * s4.w;
    }
    const float4 nv4 = *reinterpret_cast<const float4*>(newvp + l32 * 4);

    float m = -1e30f, l = 0.f;
    float4 acc[8];
#pragma unroll
    for (int u = 0; u < 8; ++u) acc[u] = make_float4(0.f, 0.f, 0.f, 0.f);

    const int STEP = nw * 16;  // 64
    for (int s0 = wid * 16; s0 < SP; s0 += STEP) {
        float4 k4[8], v4[8];
#pragma unroll
        for (int u = 0; u < 8; ++u) {
            const int p = s0 + u * 2 + half;
            const int idx = bt[p >> 4] * PBS + (p & (PBS - 1));
            const bool fresh = (idx == slot_b);
            const float* kp = k_cache + (size_t)idx * HIDDEN + h * HD;
            const float* vp = v_cache + (size_t)idx * HIDDEN + h * HD;
            k4[u] = fresh ? kn4 : *reinterpret_cast<const float4*>(kp + l32 * 4);
            v4[u] = fresh ? nv4 : *reinterpret_cast<const float4*>(vp + l32 * 4);
        }
        float sc[8];
#pragma unroll
        for (int u = 0; u < 8; ++u) {
            float d = k4[u].x * q4.x + k4[u].y * q4.y + k4[u].z * q4.z + k4[u].w * q4.w;
#pragma unroll
            for (int off = 16; off > 0; off >>= 1) d += __shfl_xor(d, off, 64);
            const int p = s0 + u * 2 + half;
            sc[u] = (base + p < len) ? d * scale : -1e30f;
        }
        float pm = sc[0];
#pragma unroll
        for (int u = 1; u < 8; ++u) pm = fmaxf(pm, sc[u]);
        const float mn = fmaxf(m, pm);
        const float r = __expf(m - mn);
        m = mn;
        l *= r;
        float pu[8];
#pragma unroll
        for (int u = 0; u < 8; ++u) {
            pu[u] = __expf(sc[u] - mn);
            l += pu[u];
        }
#pragma unroll
        for (int u = 0; u < 8; ++u) {
            acc[u].x = fmaf(pu[u], v4[u].x, acc[u].x * r);
            acc[u].y = fmaf(pu[u], v4[u].y, acc[u].y * r);
            acc[u].z = fmaf(pu[u], v4[u].z, acc[u].z * r);
            acc[u].w = fmaf(pu[u], v4[u].w, acc[u].w * r);
        }
    }
    float4 a = acc[0];
#pragma unroll
    for (int u = 1; u < 8; ++u) {
        a.x += acc[u].x; a.y += acc[u].y; a.z += acc[u].z; a.w += acc[u].w;
    }
    // merge the two halves (even/odd tokens)
    {
        const float m2 = __shfl_xor(m, 32, 64);
        const float l2 = __shfl_xor(l, 32, 64);
        float4 a2;
        a2.x = __shfl_xor(a.x, 32, 64);
        a2.y = __shfl_xor(a.y, 32, 64);
        a2.z = __shfl_xor(a.z, 32, 64);
        a2.w = __shfl_xor(a.w, 32, 64);
        const float M  = fmaxf(m, m2);
        const float e1 = __expf(m - M);
        const float e2 = __expf(m2 - M);
        l = l * e1 + l2 * e2;
        a.x = a.x * e1 + a2.x * e2;
        a.y = a.y * e1 + a2.y * e2;
        a.z = a.z * e1 + a2.z * e2;
        a.w = a.w * e1 + a2.w * e2;
        m = M;
    }
    if (half == 0) {
        *reinterpret_cast<float4*>(&stage[wid][l32 * 4]) = a;
        if (l32 == 0) { stage[wid][HD] = m; stage[wid][HD + 1] = l; }
    }
    __syncthreads();
    if (wid == 0) {
        float M4 = stage[0][HD];
#pragma unroll
        for (int w = 1; w < 4; ++w) M4 = fmaxf(M4, stage[w][HD]);
        float L = 0.f, t0 = 0.f, t1 = 0.f;
#pragma unroll
        for (int w = 0; w < 4; ++w) {
            const float e = __expf(stage[w][HD] - M4);
            L  += stage[w][HD + 1] * e;
            t0 += stage[w][lane * 2] * e;
            t1 += stage[w][lane * 2 + 1] * e;
        }
        float* po = part_o + ((size_t)bh * NSPLIT + split) * HD;
        po[lane * 2]     = t0;
        po[lane * 2 + 1] = t1;
        if (lane == 0) {
            part_ml[((size_t)bh * NSPLIT + split) * 2]     = M4;
            part_ml[((size_t)bh * NSPLIT + split) * 2 + 1] = L;
        }
    }
}

// Combine NSPLIT partials per (b,h). One block per bh, HD threads.
__global__ __launch_bounds__(HD) void attn_reduce(const float* __restrict__ part_o,
                                                  const float* __restrict__ part_ml,
                                                  float* __restrict__ attn_out) {
    const int bh = blockIdx.x;
    const int d  = threadIdx.x;
    float M = -1e30f;
#pragma unroll
    for (int i = 0; i < NSPLIT; ++i)
        M = fmaxf(M, part_ml[((size_t)bh * NSPLIT + i) * 2]);
    float L = 0.f, o = 0.f;
#pragma unroll
    for (int i = 0; i < NSPLIT; ++i) {
        const float mi = part_ml[((size_t)bh * NSPLIT + i) * 2];
        const float li = part_ml[((size_t)bh * NSPLIT + i) * 2 + 1];
        const float w  = __expf(mi - M);
        L += li * w;
        o += part_o[((size_t)bh * NSPLIT + i) * HD + d] * w;
    }
    attn_out[(size_t)bh * HD + d] = o / L;
}

extern "C" void kernel_launch(void* const* d_in, const int* in_sizes, int n_in,
                              void* d_out, int out_size, void* d_ws, size_t ws_size,
                              hipStream_t stream) {
    const float* hidden  = (const float*)d_in[0];
    const float* cosb    = (const float*)d_in[1];
    const float* sinb    = (const float*)d_in[2];
    const float* w_qkv   = (const float*)d_in[3];
    const float* b_qkv   = (const float*)d_in[4];
    const float* w_o     = (const float*)d_in[5];
    const float* k_cache = (const float*)d_in[6];
    const float* v_cache = (const float*)d_in[7];
    const int*   btab    = (const int*)d_in[8];
    const int*   slots   = (const int*)d_in[9];
    const int*   lens    = (const int*)d_in[10];

    const int B = in_sizes[0] / HIDDEN;      // 8
    const int max_blocks = in_sizes[8] / B;  // 128
    const int S = max_blocks * PBS;          // 2048

    float* qkv     = (float*)d_ws;                        // [B][QKVN] (raw, unroped)
    float* attn    = qkv + (size_t)B * QKVN;              // [B][HIDDEN]
    float* part_o  = attn + (size_t)B * HIDDEN;           // [B*NH*NSPLIT][HD]
    float* part_ml = part_o + (size_t)B * NH * NSPLIT * HD;  // [B*NH*NSPLIT][2]
    float* out     = (float*)d_out;

    // 1) qkv = hidden @ w_qkv^T + b_qkv   (double-buffered LDS x)
    gemv_db<4><<<QKVN / 16, 256, 0, stream>>>(hidden, w_qkv, b_qkv, qkv, QKVN, HIDDEN);

    // 2) paged attention partials (RoPE fused, one-pass online softmax) + reduce
    attn_part<<<B * NH * NSPLIT, 256, 0, stream>>>(qkv, cosb, sinb, k_cache, v_cache,
                                                   btab, slots, lens,
                                                   part_o, part_ml, S, max_blocks);
    attn_reduce<<<B * NH, HD, 0, stream>>>(part_o, part_ml, attn);

    // 3) out = attn @ w_o^T   (double-buffered LDS x)
    gemv_db<2><<<HIDDEN / 8, 256, 0, stream>>>(attn, w_o, nullptr, out, HIDDEN, HIDDEN);
}

// Round 12
// 191.560 us; speedup vs baseline: 1.0518x; 1.0518x over previous
//
#include <hip/hip_runtime.h>

#define NH 32
#define HD 128
#define PBS 16
#define HIDDEN (NH * HD)   // 4096
#define QKVN (3 * HIDDEN)  // 12288
#define NCH 64             // chunks per batch (s-split)
#define KC 512             // k-chunk staged in LDS (gemv)

// out[b][n] = dot(x[b,:K], W[n,:K]) + bias[n], B=8 fixed. (R8 known-good)
template <int NR>
__global__ __launch_bounds__(256) void gemv_lds(const float* __restrict__ x,
                                                const float* __restrict__ W,
                                                const float* __restrict__ bias,
                                                float* __restrict__ out,
                                                int N, int K) {
    __shared__ float xs[8][KC];
    const int tid  = threadIdx.x;
    const int lane = tid & 63;
    const int wid  = tid >> 6;
    const int n0   = blockIdx.x * (NR * 4) + wid * NR;
    const float* w0 = W + (size_t)n0 * K;

    float acc[NR][8];
#pragma unroll
    for (int r = 0; r < NR; ++r)
#pragma unroll
        for (int b = 0; b < 8; ++b) acc[r][b] = 0.f;

    for (int kc = 0; kc < K; kc += KC) {
        __syncthreads();
        {
            const int bq  = tid >> 5;
            const int t32 = tid & 31;
            const float* xb = x + (size_t)bq * K + kc;
#pragma unroll
            for (int j = 0; j < 4; ++j) {
                const int off = (t32 + j * 32) * 4;
                *reinterpret_cast<float4*>(&xs[bq][off]) =
                    *reinterpret_cast<const float4*>(xb + off);
            }
        }
        __syncthreads();
#pragma unroll
        for (int j = 0; j < 2; ++j) {
            const int kk = lane * 4 + j * 256;
            float4 w4[NR];
#pragma unroll
            for (int r = 0; r < NR; ++r)
                w4[r] = *reinterpret_cast<const float4*>(w0 + (size_t)r * K + kc + kk);
#pragma unroll
            for (int b = 0; b < 8; ++b) {
                const float4 x4 = *reinterpret_cast<const float4*>(&xs[b][kk]);
#pragma unroll
                for (int r = 0; r < NR; ++r)
                    acc[r][b] += w4[r].x * x4.x + w4[r].y * x4.y +
                                 w4[r].z * x4.z + w4[r].w * x4.w;
            }
        }
    }
#pragma unroll
    for (int r = 0; r < NR; ++r)
#pragma unroll
        for (int b = 0; b < 8; ++b)
#pragma unroll
            for (int off = 32; off > 0; off >>= 1)
                acc[r][b] += __shfl_xor(acc[r][b], off, 64);
    if (lane == 0) {
#pragma unroll
        for (int r = 0; r < NR; ++r) {
            const float bv = bias ? bias[n0 + r] : 0.f;
#pragma unroll
            for (int b = 0; b < 8; ++b)
                out[(size_t)b * N + n0 + r] = acc[r][b] + bv;
        }
    }
}

// In-place RoPE on q and k halves of qkv ws. (R8 known-good)
__global__ __launch_bounds__(256) void rope_k(float* __restrict__ qkv,
                                              const float* __restrict__ cosb,
                                              const float* __restrict__ sinb,
                                              int B) {
    const int tid = blockIdx.x * blockDim.x + threadIdx.x;
    const int total = 2 * B * NH * (HD / 2);
    if (tid >= total) return;
    const int d = tid % (HD / 2);
    const int h = (tid / (HD / 2)) % NH;
    const int b = (tid / (HD / 2) / NH) % B;
    const int part = tid / (HD / 2) / NH / B;  // 0=q, 1=k
    const float c = cosb[b * (HD / 2) + d];
    const float s = sinb[b * (HD / 2) + d];
    float* p = qkv + (size_t)b * QKVN + part * HIDDEN + h * HD + d;
    const float x1 = p[0];
    const float x2 = p[HD / 2];
    p[0]      = x1 * c - x2 * s;
    p[HD / 2] = x1 * s + x2 * c;
}

// Full-row streaming attention partial. One block per (b, chunk of 32 slots),
// 512 threads handle ALL 32 heads: thread t -> head t>>4, dims (t&15)*8..+7.
// Per slot: read the whole contiguous 16KB K row + 16KB V row (perfectly
// coalesced), 16-lane shfl score reduce, per-thread online softmax.
// No LDS in hot loop, no mid-loop barriers, no cross-wave merge.
__global__ __launch_bounds__(512) void attn_rows(const float* __restrict__ qkv,
                                                 const float* __restrict__ k_cache,
                                                 const float* __restrict__ v_cache,
                                                 const int* __restrict__ block_tables,
                                                 const int* __restrict__ slots,
                                                 const int* __restrict__ lengths,
                                                 float* __restrict__ part_o,
                                                 float* __restrict__ part_ml,
                                                 int S, int max_blocks) {
    const int chunk = blockIdx.x % NCH;
    const int b     = blockIdx.x / NCH;
    const int SCH   = S / NCH;          // 32 slots per block
    const int base  = chunk * SCH;

    __shared__ int bt[8];               // SCH/PBS = 2 used
    const int tid = threadIdx.x;
    if (tid < SCH / PBS)
        bt[tid] = block_tables[b * max_blocks + base / PBS + tid];
    __syncthreads();

    const int h   = tid >> 4;           // 0..31
    const int t16 = tid & 15;           // 0..15
    const int slot_b = slots[b];
    const int len    = lengths[b];
    const float scale = 0.088388347648318447f;  // 1/sqrt(128)

    const float* qp = qkv + (size_t)b * QKVN + h * HD + t16 * 8;
    const float4 qa = *reinterpret_cast<const float4*>(qp);
    const float4 qb = *reinterpret_cast<const float4*>(qp + 4);
    const float* newk = qkv + (size_t)b * QKVN + HIDDEN;
    const float* newv = qkv + (size_t)b * QKVN + 2 * HIDDEN;
    const int doff = h * HD + t16 * 8;

    float m = -1e30f, l = 0.f;
    float4 aa = make_float4(0.f, 0.f, 0.f, 0.f);
    float4 ab = make_float4(0.f, 0.f, 0.f, 0.f);

#pragma unroll 2
    for (int s = 0; s < SCH; ++s) {
        const int p   = base + s;
        const int idx = bt[s >> 4] * PBS + (p & (PBS - 1));
        const bool fresh = (idx == slot_b);
        const float* kr = fresh ? newk : (k_cache + (size_t)idx * HIDDEN);
        const float* vr = fresh ? newv : (v_cache + (size_t)idx * HIDDEN);
        const float4 k0 = *reinterpret_cast<const float4*>(kr + doff);
        const float4 k1 = *reinterpret_cast<const float4*>(kr + doff + 4);
        const float4 v0 = *reinterpret_cast<const float4*>(vr + doff);
        const float4 v1 = *reinterpret_cast<const float4*>(vr + doff + 4);

        float d = k0.x * qa.x + k0.y * qa.y + k0.z * qa.z + k0.w * qa.w
                + k1.x * qb.x + k1.y * qb.y + k1.z * qb.z + k1.w * qb.w;
#pragma unroll
        for (int off = 1; off < 16; off <<= 1) d += __shfl_xor(d, off, 64);
        d *= scale;

        const bool valid = (p < len);
        const float mn = valid ? fmaxf(m, d) : m;
        const float r  = __expf(m - mn);
        const float e  = valid ? __expf(d - mn) : 0.f;
        m = mn;
        l = l * r + e;
        aa.x = fmaf(e, v0.x, aa.x * r);
        aa.y = fmaf(e, v0.y, aa.y * r);
        aa.z = fmaf(e, v0.z, aa.z * r);
        aa.w = fmaf(e, v0.w, aa.w * r);
        ab.x = fmaf(e, v1.x, ab.x * r);
        ab.y = fmaf(e, v1.y, ab.y * r);
        ab.z = fmaf(e, v1.z, ab.z * r);
        ab.w = fmaf(e, v1.w, ab.w * r);
    }

    float* po = part_o + ((size_t)(b * NH + h) * NCH + chunk) * HD + t16 * 8;
    *reinterpret_cast<float4*>(po)     = aa;
    *reinterpret_cast<float4*>(po + 4) = ab;
    if (t16 == 0) {
        part_ml[((size_t)(b * NH + h) * NCH + chunk) * 2]     = m;
        part_ml[((size_t)(b * NH + h) * NCH + chunk) * 2 + 1] = l;
    }
}

// Combine NCH partials per (b,h). One block per bh, HD threads.
__global__ __launch_bounds__(HD) void attn_reduce(const float* __restrict__ part_o,
                                                  const float* __restrict__ part_ml,
                                                  float* __restrict__ attn_out) {
    const int bh = blockIdx.x;
    const int d  = threadIdx.x;
    float M = -1e30f;
#pragma unroll 8
    for (int i = 0; i < NCH; ++i)
        M = fmaxf(M, part_ml[((size_t)bh * NCH + i) * 2]);
    float L = 0.f, o = 0.f;
#pragma unroll 8
    for (int i = 0; i < NCH; ++i) {
        const float mi = part_ml[((size_t)bh * NCH + i) * 2];
        const float li = part_ml[((size_t)bh * NCH + i) * 2 + 1];
        const float w  = __expf(mi - M);
        L += li * w;
        o += part_o[((size_t)bh * NCH + i) * HD + d] * w;
    }
    attn_out[(size_t)bh * HD + d] = o / L;
}

extern "C" void kernel_launch(void* const* d_in, const int* in_sizes, int n_in,
                              void* d_out, int out_size, void* d_ws, size_t ws_size,
                              hipStream_t stream) {
    const float* hidden  = (const float*)d_in[0];
    const float* cosb    = (const float*)d_in[1];
    const float* sinb    = (const float*)d_in[2];
    const float* w_qkv   = (const float*)d_in[3];
    const float* b_qkv   = (const float*)d_in[4];
    const float* w_o     = (const float*)d_in[5];
    const float* k_cache = (const float*)d_in[6];
    const float* v_cache = (const float*)d_in[7];
    const int*   btab    = (const int*)d_in[8];
    const int*   slots   = (const int*)d_in[9];
    const int*   lens    = (const int*)d_in[10];

    const int B = in_sizes[0] / HIDDEN;      // 8
    const int max_blocks = in_sizes[8] / B;  // 128
    const int S = max_blocks * PBS;          // 2048

    float* qkv     = (float*)d_ws;                        // [B][QKVN]
    float* attn    = qkv + (size_t)B * QKVN;              // [B][HIDDEN]
    float* part_o  = attn + (size_t)B * HIDDEN;           // [B*NH*NCH][HD]
    float* part_ml = part_o + (size_t)B * NH * NCH * HD;  // [B*NH*NCH][2]
    float* out     = (float*)d_out;

    // 1) qkv = hidden @ w_qkv^T + b_qkv
    gemv_lds<4><<<QKVN / 16, 256, 0, stream>>>(hidden, w_qkv, b_qkv, qkv, QKVN, HIDDEN);

    // 2) RoPE on q and k
    {
        const int total = 2 * B * NH * (HD / 2);
        rope_k<<<(total + 255) / 256, 256, 0, stream>>>(qkv, cosb, sinb, B);
    }

    // 3) full-row streaming attention partials + reduce
    attn_rows<<<B * NCH, 512, 0, stream>>>(qkv, k_cache, v_cache, btab, slots,
                                           lens, part_o, part_ml, S, max_blocks);
    attn_reduce<<<B * NH, HD, 0, stream>>>(part_o, part_ml, attn);

    // 4) out = attn @ w_o^T
    gemv_lds<2><<<HIDDEN / 8, 256, 0, stream>>>(attn, w_o, nullptr, out, HIDDEN, HIDDEN);
}